// Round 1
// baseline (774.116 us; speedup 1.0000x reference)
//
#include <hip/hip_runtime.h>

#define DIM   512
#define NCLS  128
#define NCENT 8

// --- CSR build ---------------------------------------------------------------

__global__ __launch_bounds__(256) void hist_kernel(const int* __restrict__ dst,
                                                   int* __restrict__ cnt, int E) {
    int i = blockIdx.x * 256 + threadIdx.x;
    if (i < E) atomicAdd(&cnt[dst[i]], 1);
}

__global__ __launch_bounds__(1024) void scan_kernel(const int* __restrict__ cnt,
                                                    int* __restrict__ off,
                                                    int* __restrict__ cur, int N) {
    __shared__ int sums[1024];
    int t = threadIdx.x;
    int PER = (N + 1023) >> 10;          // elements per thread
    int base = t * PER;
    int local = 0;
    for (int k = 0; k < PER; ++k) {
        int idx = base + k;
        if (idx < N) local += cnt[idx];
    }
    sums[t] = local;
    __syncthreads();
    // Hillis-Steele inclusive scan over the 1024 per-thread sums
    for (int s = 1; s < 1024; s <<= 1) {
        int v = (t >= s) ? sums[t - s] : 0;
        __syncthreads();
        sums[t] += v;
        __syncthreads();
    }
    int run = (t == 0) ? 0 : sums[t - 1];
    for (int k = 0; k < PER; ++k) {
        int idx = base + k;
        if (idx < N) { off[idx] = run; cur[idx] = run; run += cnt[idx]; }
    }
    if (t == 0) off[N] = sums[1023];
}

__global__ __launch_bounds__(256) void scatter_kernel(const int* __restrict__ src,
                                                      const int* __restrict__ dst,
                                                      int* __restrict__ cur,
                                                      int* __restrict__ srcs, int E) {
    int i = blockIdx.x * 256 + threadIdx.x;
    if (i < E) {
        int p = atomicAdd(&cur[dst[i]], 1);
        srcs[p] = src[i];
    }
}

// --- Fused per-node: scatter-mean + router argmax + routed linear ------------

__global__ __launch_bounds__(256) void node_kernel(const float* __restrict__ h,
                                                   const int* __restrict__ off,
                                                   const int* __restrict__ srcs,
                                                   const float* __restrict__ Ws,
                                                   const float* __restrict__ Wt,
                                                   float* __restrict__ out) {
    int node = blockIdx.x;
    int t = threadIdx.x;
    __shared__ float hm[DIM];
    __shared__ float sc[NCENT];
    __shared__ int route_s;

    // scatter-mean: each thread owns 2 consecutive d-indices (256*2 = 512)
    int d0 = t * 2;
    const float* hrow = h + (size_t)node * DIM;
    float2 acc = *(const float2*)(hrow + d0);          // self loop
    int beg = off[node], end = off[node + 1];
    for (int j = beg; j < end; ++j) {
        int s = srcs[j];                               // uniform across block
        float2 v = *(const float2*)(h + (size_t)s * DIM + d0);
        acc.x += v.x; acc.y += v.y;
    }
    float inv = 1.0f / (float)(end - beg + 1);         // +1 for self loop
    hm[d0]     = acc.x * inv;
    hm[d0 + 1] = acc.y * inv;
    __syncthreads();

    // router scores: lanes 0..7 each compute one 512-dot (LDS broadcast reads)
    if (t < NCENT) {
        const float* w = Ws + t * DIM;
        float s = 0.f;
        for (int d = 0; d < DIM; d += 4) {
            float4 a = *(const float4*)(&hm[d]);
            float4 b = *(const float4*)(w + d);
            s += a.x * b.x + a.y * b.y + a.z * b.z + a.w * b.w;
        }
        sc[t] = s;
    }
    __syncthreads();
    if (t == 0) {
        int best = 0; float bv = sc[0];
        #pragma unroll
        for (int c = 1; c < NCENT; ++c)
            if (sc[c] > bv) { bv = sc[c]; best = c; }   // strict > keeps first max
        route_s = best;
    }
    __syncthreads();

    // routed expert linear: 128 outputs, one per thread t<128
    int route = route_s;
    if (t < NCLS) {
        const float* w = Wt + ((size_t)route * NCLS + t) * DIM;
        float s = 0.f;
        for (int d = 0; d < DIM; d += 4) {
            float4 a = *(const float4*)(&hm[d]);
            float4 b = *(const float4*)(w + d);
            s += a.x * b.x + a.y * b.y + a.z * b.z + a.w * b.w;
        }
        out[(size_t)node * NCLS + t] = s;
    }
}

// --- launch ------------------------------------------------------------------

extern "C" void kernel_launch(void* const* d_in, const int* in_sizes, int n_in,
                              void* d_out, int out_size, void* d_ws, size_t ws_size,
                              hipStream_t stream) {
    const float* h   = (const float*)d_in[0];
    const int*   ei  = (const int*)d_in[1];
    const float* Ws  = (const float*)d_in[2];
    const float* Wt  = (const float*)d_in[3];
    float*       out = (float*)d_out;

    int N = in_sizes[0] / DIM;
    int E = in_sizes[1] / 2;
    const int* esrc = ei;
    const int* edst = ei + E;

    int* cnt  = (int*)d_ws;        // [N]
    int* off  = cnt + N;           // [N+1]
    int* cur  = off + N + 1;       // [N]
    int* srcs = cur + N;           // [E]

    hipMemsetAsync(cnt, 0, N * sizeof(int), stream);
    hist_kernel<<<(E + 255) / 256, 256, 0, stream>>>(edst, cnt, E);
    scan_kernel<<<1, 1024, 0, stream>>>(cnt, off, cur, N);
    scatter_kernel<<<(E + 255) / 256, 256, 0, stream>>>(esrc, edst, cur, srcs, E);
    node_kernel<<<N, 256, 0, stream>>>(h, off, srcs, Ws, Wt, out);
}

// Round 2
// 488.394 us; speedup vs baseline: 1.5850x; 1.5850x over previous
//
#include <hip/hip_runtime.h>

#define DIM   512
#define NCLS  128
#define NCENT 8
#define TM    64
#define KC    32

// --- CSR build ---------------------------------------------------------------

__global__ __launch_bounds__(256) void hist_kernel(const int* __restrict__ dst,
                                                   int* __restrict__ cnt, int E) {
    int i = blockIdx.x * 256 + threadIdx.x;
    if (i < E) atomicAdd(&cnt[dst[i]], 1);
}

__global__ __launch_bounds__(1024) void scan_kernel(const int* __restrict__ cnt,
                                                    int* __restrict__ off,
                                                    int* __restrict__ cur, int N) {
    __shared__ int sums[1024];
    int t = threadIdx.x;
    int PER = (N + 1023) >> 10;
    int base = t * PER;
    int local = 0;
    for (int k = 0; k < PER; ++k) {
        int idx = base + k;
        if (idx < N) local += cnt[idx];
    }
    sums[t] = local;
    __syncthreads();
    for (int s = 1; s < 1024; s <<= 1) {
        int v = (t >= s) ? sums[t - s] : 0;
        __syncthreads();
        sums[t] += v;
        __syncthreads();
    }
    int run = (t == 0) ? 0 : sums[t - 1];
    for (int k = 0; k < PER; ++k) {
        int idx = base + k;
        if (idx < N) { off[idx] = run; cur[idx] = run; run += cnt[idx]; }
    }
    if (t == 0) off[N] = sums[1023];
}

__global__ __launch_bounds__(256) void scatter_kernel(const int* __restrict__ src,
                                                      const int* __restrict__ dst,
                                                      int* __restrict__ cur,
                                                      int* __restrict__ srcs, int E) {
    int i = blockIdx.x * 256 + threadIdx.x;
    if (i < E) {
        int p = atomicAdd(&cur[dst[i]], 1);
        srcs[p] = src[i];
    }
}

// --- Phase A: gather-mean + route (128 threads/block, float4/lane) -----------

__global__ __launch_bounds__(128) void gather_route_kernel(
        const float* __restrict__ h, const int* __restrict__ off,
        const int* __restrict__ srcs, const float* __restrict__ Ws,
        float* __restrict__ hm_g, int* __restrict__ route,
        int* __restrict__ gcnt) {
    int node = blockIdx.x;
    int t = threadIdx.x;
    __shared__ float hm_s[DIM];
    __shared__ int ssrc[128];
    __shared__ float sc[NCENT];

    int d0 = t * 4;
    float4 acc = *(const float4*)(h + (size_t)node * DIM + d0);   // self loop
    int beg = off[node], end = off[node + 1];

    for (int base = beg; base < end; base += 128) {
        int m = end - base; if (m > 128) m = 128;
        __syncthreads();
        if (t < m) ssrc[t] = srcs[base + t];
        __syncthreads();
        int j = 0;
        for (; j + 4 <= m; j += 4) {
            int s0 = ssrc[j], s1 = ssrc[j+1], s2 = ssrc[j+2], s3 = ssrc[j+3];
            float4 v0 = *(const float4*)(h + (size_t)s0 * DIM + d0);
            float4 v1 = *(const float4*)(h + (size_t)s1 * DIM + d0);
            float4 v2 = *(const float4*)(h + (size_t)s2 * DIM + d0);
            float4 v3 = *(const float4*)(h + (size_t)s3 * DIM + d0);
            acc.x += v0.x + v1.x + v2.x + v3.x;
            acc.y += v0.y + v1.y + v2.y + v3.y;
            acc.z += v0.z + v1.z + v2.z + v3.z;
            acc.w += v0.w + v1.w + v2.w + v3.w;
        }
        for (; j < m; ++j) {
            int s = ssrc[j];
            float4 v = *(const float4*)(h + (size_t)s * DIM + d0);
            acc.x += v.x; acc.y += v.y; acc.z += v.z; acc.w += v.w;
        }
    }
    float inv = 1.0f / (float)(end - beg + 1);
    acc.x *= inv; acc.y *= inv; acc.z *= inv; acc.w *= inv;
    *(float4*)(hm_g + (size_t)node * DIM + d0) = acc;
    hm_s[d0] = acc.x; hm_s[d0+1] = acc.y; hm_s[d0+2] = acc.z; hm_s[d0+3] = acc.w;
    __syncthreads();

    if (t < NCENT) {
        const float* w = Ws + t * DIM;
        float s = 0.f;
        for (int d = 0; d < DIM; d += 4) {
            float4 a = *(const float4*)(&hm_s[d]);
            float4 b = *(const float4*)(w + d);
            s += a.x * b.x + a.y * b.y + a.z * b.z + a.w * b.w;
        }
        sc[t] = s;
    }
    __syncthreads();
    if (t == 0) {
        int best = 0; float bv = sc[0];
        #pragma unroll
        for (int c = 1; c < NCENT; ++c)
            if (sc[c] > bv) { bv = sc[c]; best = c; }   // strict > = first max (jnp.argmax)
        route[node] = best;
        atomicAdd(&gcnt[best], 1);
    }
}

// --- Phase B: group nodes by route -------------------------------------------

__global__ void group_prep_kernel(const int* __restrict__ gcnt,
                                  int* __restrict__ goff, int* __restrict__ gcur,
                                  int* __restrict__ tloff) {
    if (threadIdx.x == 0 && blockIdx.x == 0) {
        int g = 0, tt = 0;
        for (int c = 0; c < NCENT; ++c) {
            goff[c] = g; gcur[c] = g; tloff[c] = tt;
            g += gcnt[c]; tt += (gcnt[c] + TM - 1) / TM;
        }
        goff[NCENT] = g; tloff[NCENT] = tt;
    }
}

__global__ __launch_bounds__(256) void group_scatter_kernel(
        const int* __restrict__ route, int* __restrict__ gcur,
        int* __restrict__ nlist, int N) {
    int i = blockIdx.x * 256 + threadIdx.x;
    if (i < N) {
        int r = route[i];
        int p = atomicAdd(&gcur[r], 1);
        nlist[p] = i;
    }
}

// --- Phase C: grouped GEMM  out[n, :] = hm[n, :] @ Wt[route(n)]^T ------------
// tile: TM=64 nodes x 128 outs, Kc=32. LDS stride 33 (conflict-free with
// o = tn + 32*j output mapping: bank = (33*o + k) % 32 = (tn + k) % 32).

__global__ __launch_bounds__(256) void gemm_kernel(
        const float* __restrict__ hm, const int* __restrict__ nlist,
        const int* __restrict__ goff, const int* __restrict__ tloff,
        const float* __restrict__ Wt, float* __restrict__ out) {
    __shared__ float a_s[TM][KC + 1];
    __shared__ float b_s[NCLS][KC + 1];

    int b = blockIdx.x;
    if (b >= tloff[NCENT]) return;
    int c = 0;
    while (b >= tloff[c + 1]) ++c;
    int row0 = goff[c] + (b - tloff[c]) * TM;
    int mrows = goff[c + 1] - row0; if (mrows > TM) mrows = TM;

    int tid = threadIdx.x;
    int tn = tid & 31;        // output lane: o = tn + 32*j
    int tm = tid >> 5;        // 0..7: nodes m = tm*8 + i

    float acc[8][4];
    #pragma unroll
    for (int i = 0; i < 8; ++i)
        #pragma unroll
        for (int j = 0; j < 4; ++j) acc[i][j] = 0.f;

    const float* wt_c = Wt + (size_t)c * NCLS * DIM;

    for (int k0 = 0; k0 < DIM; k0 += KC) {
        #pragma unroll
        for (int r = 0; r < 2; ++r) {                 // stage A: 64x32
            int cidx = tid + 256 * r;                 // 0..511
            int row = cidx >> 3;
            int kq = (cidx & 7) * 4;
            int rr = row < mrows ? row : mrows - 1;
            int nd = nlist[row0 + rr];
            float4 v = *(const float4*)(hm + (size_t)nd * DIM + k0 + kq);
            a_s[row][kq] = v.x; a_s[row][kq+1] = v.y;
            a_s[row][kq+2] = v.z; a_s[row][kq+3] = v.w;
        }
        #pragma unroll
        for (int r = 0; r < 4; ++r) {                 // stage B: 128x32
            int cidx = tid + 256 * r;                 // 0..1023
            int row = cidx >> 3;
            int kq = (cidx & 7) * 4;
            float4 v = *(const float4*)(wt_c + (size_t)row * DIM + k0 + kq);
            b_s[row][kq] = v.x; b_s[row][kq+1] = v.y;
            b_s[row][kq+2] = v.z; b_s[row][kq+3] = v.w;
        }
        __syncthreads();
        #pragma unroll
        for (int k = 0; k < KC; ++k) {
            float bv[4];
            #pragma unroll
            for (int j = 0; j < 4; ++j) bv[j] = b_s[tn + 32 * j][k];
            #pragma unroll
            for (int i = 0; i < 8; ++i) {
                float av = a_s[tm * 8 + i][k];
                #pragma unroll
                for (int j = 0; j < 4; ++j) acc[i][j] += av * bv[j];
            }
        }
        __syncthreads();
    }

    #pragma unroll
    for (int i = 0; i < 8; ++i) {
        int row = tm * 8 + i;
        if (row < mrows) {
            int nd = nlist[row0 + row];
            #pragma unroll
            for (int j = 0; j < 4; ++j)
                out[(size_t)nd * NCLS + tn + 32 * j] = acc[i][j];
        }
    }
}

// --- Fallback (round-1 fused kernel) if workspace is too small ---------------

__global__ __launch_bounds__(256) void node_kernel(const float* __restrict__ h,
                                                   const int* __restrict__ off,
                                                   const int* __restrict__ srcs,
                                                   const float* __restrict__ Ws,
                                                   const float* __restrict__ Wt,
                                                   float* __restrict__ out) {
    int node = blockIdx.x;
    int t = threadIdx.x;
    __shared__ float hm[DIM];
    __shared__ float sc[NCENT];
    __shared__ int route_s;

    int d0 = t * 2;
    const float* hrow = h + (size_t)node * DIM;
    float2 acc = *(const float2*)(hrow + d0);
    int beg = off[node], end = off[node + 1];
    for (int j = beg; j < end; ++j) {
        int s = srcs[j];
        float2 v = *(const float2*)(h + (size_t)s * DIM + d0);
        acc.x += v.x; acc.y += v.y;
    }
    float inv = 1.0f / (float)(end - beg + 1);
    hm[d0] = acc.x * inv; hm[d0 + 1] = acc.y * inv;
    __syncthreads();
    if (t < NCENT) {
        const float* w = Ws + t * DIM;
        float s = 0.f;
        for (int d = 0; d < DIM; d += 4) {
            float4 a = *(const float4*)(&hm[d]);
            float4 b = *(const float4*)(w + d);
            s += a.x * b.x + a.y * b.y + a.z * b.z + a.w * b.w;
        }
        sc[t] = s;
    }
    __syncthreads();
    if (t == 0) {
        int best = 0; float bv = sc[0];
        #pragma unroll
        for (int c = 1; c < NCENT; ++c)
            if (sc[c] > bv) { bv = sc[c]; best = c; }
        route_s = best;
    }
    __syncthreads();
    int route = route_s;
    if (t < NCLS) {
        const float* w = Wt + ((size_t)route * NCLS + t) * DIM;
        float s = 0.f;
        for (int d = 0; d < DIM; d += 4) {
            float4 a = *(const float4*)(&hm[d]);
            float4 b = *(const float4*)(w + d);
            s += a.x * b.x + a.y * b.y + a.z * b.z + a.w * b.w;
        }
        out[(size_t)node * NCLS + t] = s;
    }
}

// --- launch ------------------------------------------------------------------

extern "C" void kernel_launch(void* const* d_in, const int* in_sizes, int n_in,
                              void* d_out, int out_size, void* d_ws, size_t ws_size,
                              hipStream_t stream) {
    const float* h   = (const float*)d_in[0];
    const int*   ei  = (const int*)d_in[1];
    const float* Ws  = (const float*)d_in[2];
    const float* Wt  = (const float*)d_in[3];
    float*       out = (float*)d_out;

    int N = in_sizes[0] / DIM;
    int E = in_sizes[1] / 2;
    const int* esrc = ei;
    const int* edst = ei + E;

    int* wsp   = (int*)d_ws;
    int* cnt   = wsp;                 // N
    int* gcnt  = cnt + N;             // 8
    int* gcur  = gcnt + NCENT;        // 8
    int* off   = gcur + NCENT;        // N+1
    int* cur   = off + N + 1;         // N
    int* srcs  = cur + N;             // E
    int* route = srcs + E;            // N
    int* goff  = route + N;           // 9
    int* tloff = goff + NCENT + 1;    // 9
    int* nlist = tloff + NCENT + 1;   // N
    size_t int_words = (size_t)(5 * N + E + 2 * NCENT + 3 * (NCENT + 1) + 1);
    size_t hm_off = ((int_words * 4 + 255) & ~(size_t)255);
    float* hm = (float*)((char*)d_ws + hm_off);
    size_t need = hm_off + (size_t)N * DIM * sizeof(float);

    hipMemsetAsync(cnt, 0, (size_t)(N + NCENT) * sizeof(int), stream);
    hist_kernel<<<(E + 255) / 256, 256, 0, stream>>>(edst, cnt, E);
    scan_kernel<<<1, 1024, 0, stream>>>(cnt, off, cur, N);
    scatter_kernel<<<(E + 255) / 256, 256, 0, stream>>>(esrc, edst, cur, srcs, E);

    if (ws_size >= need) {
        gather_route_kernel<<<N, 128, 0, stream>>>(h, off, srcs, Ws, hm, route, gcnt);
        group_prep_kernel<<<1, 64, 0, stream>>>(gcnt, goff, gcur, tloff);
        group_scatter_kernel<<<(N + 255) / 256, 256, 0, stream>>>(route, gcur, nlist, N);
        int maxtiles = N / TM + NCENT + 1;
        gemm_kernel<<<maxtiles, 256, 0, stream>>>(hm, nlist, goff, tloff, Wt, out);
    } else {
        node_kernel<<<N, 256, 0, stream>>>(h, off, srcs, Ws, Wt, out);
    }
}